// Round 6
// baseline (316.247 us; speedup 1.0000x reference)
//
#include <hip/hip_runtime.h>
#include <cfloat>
#include <math.h>

// ---------------- problem constants ----------------
#define ESTR 516            // eT LDS row stride (dwords)
#define SMEM_A ((64*ESTR + 8*64*8) * 4)     // eT + 8 wave-private x slices = 148480 B

// output layout (flat concat, all float32)
#define O_LOSS 0
#define O_Q    1ull                         // 8388608 elements, NCHW
#define O_PERP 8388609ull
#define O_DIST 8388610ull                   // 131072 x 512
#define O_IDX  75497474ull                  // 131072
#define O_ENC  75628546ull                  // 131072 x 512

// ws layout: [0,2048) uint hist[512]; [2048,2056) double loss_sum; [2064,...) float sume2[512]

// ---------------- prep: zero accumulators, compute ||e_k||^2 (numpy pairwise order) ----
__global__ void vq_prep(const float* __restrict__ emb, unsigned int* __restrict__ hist,
                        double* __restrict__ lsum, float* __restrict__ sume2) {
    int k = threadIdx.x;   // 512 threads
    hist[k] = 0u;
    if (k == 0) *lsum = 0.0;
    float x[64];
    const float4* e4 = (const float4*)(emb + k * 64);
#pragma unroll
    for (int i = 0; i < 16; ++i) {
        float4 v = e4[i];
        x[4*i+0] = v.x; x[4*i+1] = v.y; x[4*i+2] = v.z; x[4*i+3] = v.w;
    }
    float r[8];
#pragma unroll
    for (int j = 0; j < 8; ++j) r[j] = x[j] * x[j];
#pragma unroll
    for (int i = 8; i < 64; i += 8)
#pragma unroll
        for (int j = 0; j < 8; ++j) r[j] += x[i+j] * x[i+j];
    sume2[k] = ((r[0]+r[1])+(r[2]+r[3])) + ((r[4]+r[5])+(r[6]+r[7]));
}

// ---------------- kernel A: GEMM + argmin + dist + idx (compute-bound) ----------------
__global__ __launch_bounds__(512, 2)
void vq_gemm(const float* __restrict__ in, const float* __restrict__ emb,
             float* __restrict__ out, const float* __restrict__ sume2g) {
    extern __shared__ float smem[];
    float* eT = smem;                                  // [64][ESTR] shared read-only
    const int tid  = threadIdx.x;
    const int lane = tid & 63;
    const int w    = tid >> 6;                         // wave 0..7
    float* xw = smem + 64 * ESTR + w * 512;            // wave-private [d=64][r=8]

    const int n   = blockIdx.x >> 3;                   // image
    const int hwB = ((blockIdx.x & 7) << 9) + (w << 6);// wave's 64-hw span
    const int jS  = lane & 7, mS = lane >> 3;          // sumx2 lane map

    // ---- prologue loads
    float4 ev16[16];
    {
        const float4* e4 = (const float4*)emb;
#pragma unroll
        for (int it = 0; it < 16; ++it) ev16[it] = e4[tid + 512 * it];
    }
    float4 se0 = *(const float4*)(sume2g + 4 * lane);
    float4 se1 = *(const float4*)(sume2g + 256 + 4 * lane);
    const float se[8] = {se0.x, se0.y, se0.z, se0.w, se1.x, se1.y, se1.z, se1.w};

    // ---- stage codebook transposed: eT[d][k] = emb[k*64+d]
#pragma unroll 4
    for (int it = 0; it < 16; ++it) {
        int idx4 = tid + 512 * it;
        int k  = idx4 >> 4;
        int dq = (idx4 & 15) << 2;
        float4 v = ev16[it];
        eT[(dq+0)*ESTR + k] = v.x;
        eT[(dq+1)*ESTR + k] = v.y;
        eT[(dq+2)*ESTR + k] = v.z;
        eT[(dq+3)*ESTR + k] = v.w;
    }
    __syncthreads();     // ONLY barrier. Waves fully independent after this.

    // lane l carries channel c=l of its wave's rows
    const float* xbase = in + (size_t)(n * 64 + lane) * 4096 + hwB;
    float4 pf0 = *(const float4*)(xbase);
    float4 pf1 = *(const float4*)(xbase + 4);

#pragma unroll 1
    for (int t = 0; t < 8; ++t) {
        // ---- commit µtile t (wave-private: program order + lgkmcnt only)
        *(float4*)&xw[lane * 8]     = pf0;
        *(float4*)&xw[lane * 8 + 4] = pf1;

        // ---- sumx2, numpy pairwise tree via 3-step butterfly (R5-proven)
        float rj;
        { float v = xw[jS * 8 + mS]; rj = v * v; }
#pragma unroll
        for (int i = 1; i < 8; ++i) { float v = xw[(8*i + jS) * 8 + mS]; rj += v * v; }
        rj += __shfl_xor(rj, 1, 64);
        rj += __shfl_xor(rj, 2, 64);
        rj += __shfl_xor(rj, 4, 64);
        float sxv[8];
#pragma unroll
        for (int m = 0; m < 8; ++m) sxv[m] = __shfl(rj, 8 * m, 64);

        // ---- GEMM: 8 rows x 8 k per thread; 4 DS (2 bcast x + 2 contig e) per d
        float acc[8][8];
#pragma unroll
        for (int m = 0; m < 8; ++m)
#pragma unroll
            for (int kk = 0; kk < 8; ++kk) acc[m][kk] = 0.0f;

#pragma unroll 4
        for (int d = 0; d < 64; ++d) {
            float4 x0 = *(const float4*)&xw[d * 8];                      // rows 0..3
            float4 x1 = *(const float4*)&xw[d * 8 + 4];                  // rows 4..7
            float4 e0 = *(const float4*)&eT[d * ESTR + 4 * lane];        // k 4L..
            float4 e1 = *(const float4*)&eT[d * ESTR + 256 + 4 * lane];  // k 256+4L..
            float xv[8]  = {x0.x, x0.y, x0.z, x0.w, x1.x, x1.y, x1.z, x1.w};
            float evv[8] = {e0.x, e0.y, e0.z, e0.w, e1.x, e1.y, e1.z, e1.w};
#pragma unroll
            for (int m = 0; m < 8; ++m)
#pragma unroll
                for (int kk = 0; kk < 8; ++kk)
                    acc[m][kk] = fmaf(xv[m], evv[kk], acc[m][kk]);
        }

        // ---- prefetch next µtile BEFORE this tile's stores (loads older than
        //      stores in the vmcnt queue -> the ds_write wait never drains stores)
        {
            int tn = (t + 1) & 7;
            pf0 = *(const float4*)(xbase + 8 * tn);
            pf1 = *(const float4*)(xbase + 8 * tn + 4);
            __builtin_amdgcn_sched_barrier(0);
        }

        // ---- distances, stores, lex argmin (R5-proven formulas)
        const int row0 = (n << 12) + hwB + 8 * t;
        int bkk[8];
#pragma unroll
        for (int m = 0; m < 8; ++m) {
            float dv[8];
            float bd = FLT_MAX; int bki = 0;
#pragma unroll
            for (int kk = 0; kk < 8; ++kk) {
                int k = ((kk & 4) << 6) + 4 * lane + (kk & 3);
                float ts = sxv[m] + se[kk];            // fl(a+b) (np broadcast add)
                float dist = ts - 2.0f * acc[m][kk];   // fl(t - 2m)
                dv[kk] = dist;
                if (dist < bd) { bd = dist; bki = k; } // in-lane k ascending
            }
            float* dout = out + O_DIST + (size_t)(row0 + m) * 512;
            *(float4*)&dout[4 * lane]       = make_float4(dv[0], dv[1], dv[2], dv[3]);
            *(float4*)&dout[256 + 4 * lane] = make_float4(dv[4], dv[5], dv[6], dv[7]);
#pragma unroll
            for (int s = 1; s <= 32; s <<= 1) {        // lex butterfly
                float od = __shfl_xor(bd, s, 64);
                int   ok = __shfl_xor(bki, s, 64);
                if (od < bd || (od == bd && ok < bki)) { bd = od; bki = ok; }
            }
            bkk[m] = bki;
        }

        // kbest for row (lane&7) via static select tree (no runtime reg indexing)
        int s01 = (lane & 1) ? bkk[1] : bkk[0];
        int s23 = (lane & 1) ? bkk[3] : bkk[2];
        int s45 = (lane & 1) ? bkk[5] : bkk[4];
        int s67 = (lane & 1) ? bkk[7] : bkk[6];
        int s03 = (lane & 2) ? s23 : s01;
        int s47 = (lane & 2) ? s67 : s45;
        const int kbm = (lane & 4) ? s47 : s03;
        if (lane < 8) out[O_IDX + row0 + lane] = (float)kbm;
    }
}

// ---------------- kernel B: enc + q + loss + hist (write-bound streaming) ----------
__global__ __launch_bounds__(256)
void vq_scatter(const float* __restrict__ in, const float* __restrict__ emb,
                float* __restrict__ out, unsigned int* __restrict__ hist,
                double* __restrict__ lsum) {
    __shared__ int   sIdx[64];
    __shared__ float eL[64][65];          // gathered e-rows, padded
    __shared__ double part[4];

    const int tid = threadIdx.x;          // 256
    const int n   = blockIdx.x >> 6;
    const int hw0 = (blockIdx.x & 63) << 6;
    const int rowbase = (n << 12) + hw0;

    if (tid < 64) {
        int kb = (int)out[O_IDX + rowbase + tid];   // written by kernel A (exact)
        sIdx[tid] = kb;
        atomicAdd(&hist[kb], 1u);
    }
    __syncthreads();

    // gather e-rows coalescedly: one 256B contiguous read per (wave, row)
    const int rg = tid >> 6, cg = tid & 63;
#pragma unroll 4
    for (int i = 0; i < 16; ++i) {
        int r = 4 * i + rg;
        eL[r][cg] = emb[(size_t)sIdx[r] * 64 + cg];
    }
    __syncthreads();

    // one-hot encodings: 1KB contiguous float4 stores
#pragma unroll 4
    for (int i = 0; i < 32; ++i) {
        int f4 = tid + (i << 8);                     // 0..8191
        int r  = f4 >> 7;
        int k0 = (f4 & 127) << 2;
        int kb = sIdx[r];
        float v0 = (k0     == kb) ? 1.0f : 0.0f;
        float v1 = (k0 + 1 == kb) ? 1.0f : 0.0f;
        float v2 = (k0 + 2 == kb) ? 1.0f : 0.0f;
        float v3 = (k0 + 3 == kb) ? 1.0f : 0.0f;
        *(float4*)(out + O_ENC + (size_t)(rowbase + r) * 512 + k0)
            = make_float4(v0, v1, v2, v3);
    }

    // quantized (straight-through, NCHW) + loss partial
    double lacc = 0.0;
    const int h = tid & 63, cq = tid >> 6;
#pragma unroll 4
    for (int i = 0; i < 16; ++i) {
        int c = 4 * i + cq;
        size_t gi = (size_t)(n * 64 + c) * 4096 + hw0 + h;
        float x   = in[gi];
        float dlt = eL[h][c] - x;                    // fl(q-x), as reference
        lacc += (double)(dlt * dlt);
        out[O_Q + gi] = x + dlt;                     // x + (q-x)
    }

    double v = lacc;
    for (int s = 32; s >= 1; s >>= 1) v += __shfl_down(v, s, 64);
    if ((tid & 63) == 0) part[tid >> 6] = v;
    __syncthreads();
    if (tid == 0) atomicAdd(lsum, part[0] + part[1] + part[2] + part[3]);
}

// ---------------- final: perplexity + loss scalars ----------------
__global__ void vq_final(const unsigned int* __restrict__ hist,
                         const double* __restrict__ lsum, float* __restrict__ out) {
    __shared__ double part[8];
    int k = threadIdx.x;                    // 512 threads
    float p = (float)hist[k] / 131072.0f;   // exact (count * 2^-17)
    double v = (double)(p * logf(p + 1e-10f));
    for (int s = 32; s >= 1; s >>= 1) v += __shfl_down(v, s, 64);
    if ((k & 63) == 0) part[k >> 6] = v;
    __syncthreads();
    if (k == 0) {
        double S = 0.0;
#pragma unroll
        for (int i = 0; i < 8; ++i) S += part[i];
        out[O_PERP] = (float)exp(-S);
        float vl = (float)(*lsum / 8388608.0);
        out[O_LOSS] = vl + 0.25f * vl;      // q_latent + 0.25 * e_latent (equal values)
    }
}

// ---------------- launcher ----------------
extern "C" void kernel_launch(void* const* d_in, const int* in_sizes, int n_in,
                              void* d_out, int out_size, void* d_ws, size_t ws_size,
                              hipStream_t stream) {
    const float* in  = (const float*)d_in[0];   // (32,64,64,64) NCHW fp32
    const float* emb = (const float*)d_in[1];   // (512,64) fp32
    float* out = (float*)d_out;

    unsigned int* hist = (unsigned int*)d_ws;                    // 512 * 4 B
    double* lsum = (double*)((char*)d_ws + 2048);                // 8 B
    float* sume2 = (float*)((char*)d_ws + 2064);                 // 512 * 4 B

    hipFuncSetAttribute((const void*)vq_gemm,
                        hipFuncAttributeMaxDynamicSharedMemorySize, SMEM_A);

    vq_prep<<<1, 512, 0, stream>>>(emb, hist, lsum, sume2);
    vq_gemm<<<256, 512, SMEM_A, stream>>>(in, emb, out, sume2);
    vq_scatter<<<2048, 256, 0, stream>>>(in, emb, out, hist, lsum);
    vq_final<<<1, 512, 0, stream>>>(hist, lsum, out);
}

// Round 8
// 259.600 us; speedup vs baseline: 1.2182x; 1.2182x over previous
//
#include <hip/hip_runtime.h>
#include <cfloat>
#include <math.h>

// ---------------- problem constants ----------------
// output layout (flat concat, all float32)
#define O_LOSS 0
#define O_Q    1ull                         // 8388608 elements, NCHW
#define O_PERP 8388609ull
#define O_DIST 8388610ull                   // 131072 x 512
#define O_IDX  75497474ull                  // 131072
#define O_ENC  75628546ull                  // 131072 x 512

// ws layout (bytes): [0,2048) uint hist[512]; [2048,2056) double lsum;
// [2064,4112) float sume2[512]; [8192, 8192+512K) float sumx2[131072];
// [1M, 1M+8M) float2 cand[131072][8]
#define WS_SUMX2 8192
#define WS_CAND  (1u << 20)

#define SMEM_A ((64*256 + 64*64) * 4)       // eT 64KB + xT 16KB = 81920 B (2 blocks/CU)

typedef float f32x2 __attribute__((ext_vector_type(2)));

// LDS-only barrier: never drains vmcnt, stores keep flowing
__device__ __forceinline__ void bar_lgkm() {
    asm volatile("s_waitcnt lgkmcnt(0)\n\ts_barrier" ::: "memory");
}

// ---------------- prep_e: zero accumulators, ||e_k||^2 (numpy pairwise order) ----
__global__ void vq_prep_e(const float* __restrict__ emb, unsigned int* __restrict__ hist,
                          double* __restrict__ lsum, float* __restrict__ sume2) {
    int k = threadIdx.x;   // 512 threads
    hist[k] = 0u;
    if (k == 0) *lsum = 0.0;
    float x[64];
    const float4* e4 = (const float4*)(emb + k * 64);
#pragma unroll
    for (int i = 0; i < 16; ++i) {
        float4 v = e4[i];
        x[4*i+0] = v.x; x[4*i+1] = v.y; x[4*i+2] = v.z; x[4*i+3] = v.w;
    }
    float r[8];
#pragma unroll
    for (int j = 0; j < 8; ++j) r[j] = x[j] * x[j];
#pragma unroll
    for (int i = 8; i < 64; i += 8)
#pragma unroll
        for (int j = 0; j < 8; ++j) r[j] += x[i+j] * x[i+j];
    sume2[k] = ((r[0]+r[1])+(r[2]+r[3])) + ((r[4]+r[5])+(r[6]+r[7]));
}

// ---------------- prep_x: ||x_row||^2 (numpy pairwise order), coalesced ----------
__global__ __launch_bounds__(256)
void vq_prep_x(const float* __restrict__ in, float* __restrict__ sumx2) {
    int row = blockIdx.x * 256 + threadIdx.x;          // 131072 rows
    const float* base = in + ((size_t)(row >> 12) << 18) + (row & 4095);
    float r8[8];
#pragma unroll
    for (int j = 0; j < 8; ++j) { float v = base[(size_t)j << 12]; r8[j] = v * v; }
#pragma unroll
    for (int i = 8; i < 64; i += 8)
#pragma unroll
        for (int j = 0; j < 8; ++j) { float v = base[(size_t)(i + j) << 12]; r8[j] += v * v; }
    sumx2[row] = ((r8[0]+r8[1])+(r8[2]+r8[3])) + ((r8[4]+r8[5])+(r8[6]+r8[7]));
}

// ---------------- kernel A: GEMM + dist + per-wave argmin candidates --------------
// block = 64 rows x 256-k half; 256 threads (4 waves, k-split 64 k each)
__global__ __launch_bounds__(256, 2)
void vq_gemm(const float* __restrict__ in, const float* __restrict__ emb,
             float* __restrict__ out, const float* __restrict__ sume2g,
             const float* __restrict__ sumx2g, float2* __restrict__ cand) {
    extern __shared__ float smem[];
    float* eT = smem;              // [64 d][256 k-half]
    float* xT = smem + 64 * 256;   // [64 c][64 row]

    const int tid  = threadIdx.x;
    const int w    = tid >> 6;                 // wave 0..3
    const int lane = tid & 63;
    const int ri   = lane >> 3;                // row group (rows 8ri+m)
    const int ki   = lane & 7;                 // k subgroup
    const int rt   = blockIdx.x >> 1;          // row tile 0..2047
    const int h    = blockIdx.x & 1;           // k half
    const int row0 = rt << 6;
    const int n    = row0 >> 12;
    const int hw0  = row0 & 4095;
    const int kb   = (h << 8) + (w << 6) + (ki << 3);   // this thread's first k

    // ---- prologue: ALL global loads (none after the barrier) ----
    float4 eg[16];
    const float* ebase = emb + (size_t)((h << 8) + tid) * 64;
#pragma unroll
    for (int it = 0; it < 16; ++it) eg[it] = *(const float4*)(ebase + 4 * it);
    float4 xg[4];
#pragma unroll
    for (int ii = 0; ii < 4; ++ii) {
        int f4i = tid + (ii << 8);             // 0..1023
        int c = f4i >> 4, hq = (f4i & 15) << 2;
        xg[ii] = *(const float4*)(in + ((size_t)(n * 64 + c) << 12) + hw0 + hq);
    }
    float  sxl = sumx2g[row0 + lane];
    float4 sea = *(const float4*)(sume2g + kb);
    float4 seb = *(const float4*)(sume2g + kb + 4);
    const float se[8] = {sea.x, sea.y, sea.z, sea.w, seb.x, seb.y, seb.z, seb.w};

    // ---- stage: eT[d][k_local] (conflict-free b32 columns), xT[c][row] ----
#pragma unroll
    for (int it = 0; it < 16; ++it) {
        eT[(4*it+0)*256 + tid] = eg[it].x;
        eT[(4*it+1)*256 + tid] = eg[it].y;
        eT[(4*it+2)*256 + tid] = eg[it].z;
        eT[(4*it+3)*256 + tid] = eg[it].w;
    }
#pragma unroll
    for (int ii = 0; ii < 4; ++ii) {
        int f4i = tid + (ii << 8);
        int c = f4i >> 4, hq = (f4i & 15) << 2;
        *(float4*)&xT[c * 64 + hq] = xg[ii];
    }
    __syncthreads();

    float sx[8];
#pragma unroll
    for (int m = 0; m < 8; ++m) sx[m] = __shfl(sxl, 8 * ri + m, 64);

    // ---- GEMM: 8 rows x 8 k per thread, m packed in f32x2 (v_pk_fma_f32) ----
    f32x2 acc[8][4];
#pragma unroll
    for (int kk = 0; kk < 8; ++kk)
#pragma unroll
        for (int mp = 0; mp < 4; ++mp) acc[kk][mp] = (f32x2){0.0f, 0.0f};

    const float* xr = xT + 8 * ri;
    const float* er = eT + (w << 6) + (ki << 3);   // FIX R7: include wave k-offset w*64
#pragma unroll 2
    for (int d = 0; d < 64; ++d) {
        float4 xa = *(const float4*)(xr + d * 64);
        float4 xb = *(const float4*)(xr + d * 64 + 4);
        float4 ea = *(const float4*)(er + d * 256);
        float4 eb = *(const float4*)(er + d * 256 + 4);
        f32x2 xp[4] = {{xa.x, xa.y}, {xa.z, xa.w}, {xb.x, xb.y}, {xb.z, xb.w}};
        float ev[8] = {ea.x, ea.y, ea.z, ea.w, eb.x, eb.y, eb.z, eb.w};
#pragma unroll
        for (int kk = 0; kk < 8; ++kk) {
            f32x2 e2 = {ev[kk], ev[kk]};
#pragma unroll
            for (int mp = 0; mp < 4; ++mp)
                acc[kk][mp] = __builtin_elementwise_fma(xp[mp], e2, acc[kk][mp]);
        }
    }

    // ---- distances, stores, per-wave lex argmin over its 64-k slice ----
    float bd[8]; int bk[8];
#pragma unroll
    for (int m = 0; m < 8; ++m) {
        const int mp = m >> 1;
        float dv[8];
        float bdm = FLT_MAX; int bkm = 0;
#pragma unroll
        for (int kk = 0; kk < 8; ++kk) {
            float a = (m & 1) ? acc[kk][mp].y : acc[kk][mp].x;
            float ts = sx[m] + se[kk];             // fl(a+b) (np broadcast add)
            float di = ts - 2.0f * a;              // fl(t - 2m)
            dv[kk] = di;
            if (di < bdm) { bdm = di; bkm = kb + kk; }   // k ascending
        }
        float* dout = out + O_DIST + (size_t)(row0 + 8 * ri + m) * 512 + kb;
        *(float4*)dout       = make_float4(dv[0], dv[1], dv[2], dv[3]);
        *(float4*)(dout + 4) = make_float4(dv[4], dv[5], dv[6], dv[7]);
        // reduce across the 8 ki lanes sharing this row (lex tie-break)
#pragma unroll
        for (int s = 1; s <= 4; s <<= 1) {
            float od = __shfl_xor(bdm, s, 64);
            int   ok = __shfl_xor(bkm, s, 64);
            if (od < bdm || (od == bdm && ok < bkm)) { bdm = od; bkm = ok; }
        }
        bd[m] = bdm; bk[m] = bkm;
    }
    if (ki == 0) {
#pragma unroll
        for (int m = 0; m < 8; ++m)
            cand[(size_t)(row0 + 8 * ri + m) * 8 + (h * 4 + w)]
                = make_float2(bd[m], (float)bk[m]);
    }
}

// ---------------- kernel B: combine cands -> idx, enc, q, hist, loss ------------
__global__ __launch_bounds__(256, 4)
void vq_emit(const float* __restrict__ in, const float* __restrict__ emb,
             float* __restrict__ out, const float2* __restrict__ cand,
             unsigned int* __restrict__ hist, double* __restrict__ lsum) {
    __shared__ int    sIdx[64];
    __shared__ float  eL[64][65];
    __shared__ double part[4];

    const int tid  = threadIdx.x;              // 256
    const int row0 = blockIdx.x << 6;          // 2048 blocks x 64 rows
    const int n    = row0 >> 12;
    const int hw0  = row0 & 4095;
    const int hL   = tid & 63, cq = tid >> 6;

    // hoist all x reads (before any stores)
    float xv[16];
#pragma unroll
    for (int i = 0; i < 16; ++i) {
        int c = 4 * i + cq;
        xv[i] = in[((size_t)(n * 64 + c) << 12) + hw0 + hL];
    }

    if (tid < 64) {
        const float4* cp = (const float4*)(cand + (size_t)(row0 + tid) * 8);
        float bdm = FLT_MAX, bkf = 0.0f;
#pragma unroll
        for (int j = 0; j < 4; ++j) {          // k-ascending candidate order
            float4 c4 = cp[j];
            if (c4.x < bdm || (c4.x == bdm && c4.y < bkf)) { bdm = c4.x; bkf = c4.y; }
            if (c4.z < bdm || (c4.z == bdm && c4.w < bkf)) { bdm = c4.z; bkf = c4.w; }
        }
        int kbst = (int)bkf;
        sIdx[tid] = kbst;
        out[O_IDX + row0 + tid] = bkf;
        atomicAdd(&hist[kbst], 1u);
    }
    __syncthreads();

    // issue e-row gather loads (coalesced 256B per row, L2-hot) ...
    float ev[16];
#pragma unroll
    for (int i = 0; i < 16; ++i)
        ev[i] = emb[(size_t)sIdx[4 * i + cq] * 64 + hL];

    // ... then one-hot stores (loads are older than stores in the vm queue)
#pragma unroll 4
    for (int i = 0; i < 32; ++i) {
        int f4i = tid + (i << 8);              // 0..8191
        int r   = f4i >> 7;
        int k0  = (f4i & 127) << 2;
        int kbr = sIdx[r];
        *(float4*)(out + O_ENC + (size_t)(row0 + r) * 512 + k0) = make_float4(
            (k0     == kbr) ? 1.0f : 0.0f, (k0 + 1 == kbr) ? 1.0f : 0.0f,
            (k0 + 2 == kbr) ? 1.0f : 0.0f, (k0 + 3 == kbr) ? 1.0f : 0.0f);
    }

    // commit gathered e rows to LDS
#pragma unroll
    for (int i = 0; i < 16; ++i) eL[4 * i + cq][hL] = ev[i];
    bar_lgkm();

    // quantized (straight-through, NCHW) + loss partial
    double lacc = 0.0;
#pragma unroll 4
    for (int i = 0; i < 16; ++i) {
        int c = 4 * i + cq;
        float x = xv[i];
        float d = eL[hL][c] - x;               // fl(q-x), as reference
        lacc += (double)(d * d);
        out[O_Q + ((size_t)(n * 64 + c) << 12) + hw0 + hL] = x + d;   // x + (q-x)
    }

    double v = lacc;
    for (int s = 32; s >= 1; s >>= 1) v += __shfl_down(v, s, 64);
    if ((tid & 63) == 0) part[tid >> 6] = v;
    bar_lgkm();
    if (tid == 0) atomicAdd(lsum, part[0] + part[1] + part[2] + part[3]);
}

// ---------------- final: perplexity + loss scalars ----------------
__global__ void vq_final(const unsigned int* __restrict__ hist,
                         const double* __restrict__ lsum, float* __restrict__ out) {
    __shared__ double part[8];
    int k = threadIdx.x;                    // 512 threads
    float p = (float)hist[k] / 131072.0f;   // exact (count * 2^-17)
    double v = (double)(p * logf(p + 1e-10f));
    for (int s = 32; s >= 1; s >>= 1) v += __shfl_down(v, s, 64);
    if ((k & 63) == 0) part[k >> 6] = v;
    __syncthreads();
    if (k == 0) {
        double S = 0.0;
#pragma unroll
        for (int i = 0; i < 8; ++i) S += part[i];
        out[O_PERP] = (float)exp(-S);
        float vl = (float)(*lsum / 8388608.0);
        out[O_LOSS] = vl + 0.25f * vl;      // q_latent + 0.25 * e_latent (equal values)
    }
}

// ---------------- launcher ----------------
extern "C" void kernel_launch(void* const* d_in, const int* in_sizes, int n_in,
                              void* d_out, int out_size, void* d_ws, size_t ws_size,
                              hipStream_t stream) {
    const float* in  = (const float*)d_in[0];   // (32,64,64,64) NCHW fp32
    const float* emb = (const float*)d_in[1];   // (512,64) fp32
    float* out = (float*)d_out;

    unsigned int* hist = (unsigned int*)d_ws;
    double* lsum  = (double*)((char*)d_ws + 2048);
    float*  sume2 = (float*)((char*)d_ws + 2064);
    float*  sumx2 = (float*)((char*)d_ws + WS_SUMX2);
    float2* cand  = (float2*)((char*)d_ws + WS_CAND);

    hipFuncSetAttribute((const void*)vq_gemm,
                        hipFuncAttributeMaxDynamicSharedMemorySize, SMEM_A);

    vq_prep_e<<<1, 512, 0, stream>>>(emb, hist, lsum, sume2);
    vq_prep_x<<<512, 256, 0, stream>>>(in, sumx2);
    vq_gemm<<<4096, 256, SMEM_A, stream>>>(in, emb, out, sume2, sumx2, cand);
    vq_emit<<<2048, 256, 0, stream>>>(in, emb, out, cand, hist, lsum);
    vq_final<<<1, 512, 0, stream>>>(hist, lsum, out);
}